// Round 14
// baseline (62.146 us; speedup 1.0000x reference)
//
#include <hip/hip_runtime.h>
#include <hip/hip_bf16.h>

typedef __bf16 v8bf __attribute__((ext_vector_type(8)));
typedef float f32x16 __attribute__((ext_vector_type(16)));
typedef unsigned int uint;
typedef unsigned short ushort;

#define GLOAD16(gsrc, ldst)                                                       \
  __builtin_amdgcn_global_load_lds(                                               \
      (const __attribute__((address_space(1))) unsigned int*)(gsrc),              \
      (__attribute__((address_space(3))) unsigned int*)(ldst), 16, 0, 0)

__device__ inline f32x16 zero16() {
  f32x16 z;
#pragma unroll
  for (int i = 0; i < 16; i++) z[i] = 0.f;
  return z;
}

__device__ inline uint pack_bf16(float a, float b) {
  union { __bf16 h[2]; uint u; } c;
  c.h[0] = (__bf16)a;
  c.h[1] = (__bf16)b;
  return c.u;
}

// ---------------------------------------------------------------------------
// Kernel 0: Wt_s = transpose of [Wq|Wk|Wv] -> bf16, PRE-SWIZZLED:
// element (n,k) at byte n*2048 + (k>>6)*128 + (((k&63)*2) ^ ((n&7)<<4)).
// (validated since R5 — unchanged)
// ---------------------------------------------------------------------------
__global__ void prep_wt(const float* __restrict__ Wq, const float* __restrict__ Wk,
                        const float* __restrict__ Wv, char* __restrict__ Wt_s) {
  __shared__ __bf16 tile[64][74];
  const int mat = blockIdx.x >> 4;
  const int c0 = (blockIdx.x & 15) * 64;
  const float* src = (mat == 0) ? Wq : (mat == 1) ? Wk : Wv;
  const int t = threadIdx.x;  // 256 threads
  {
    const int r = t >> 2;
    const int ch = (t & 3) * 16;
    const float4* s4 = (const float4*)(src + (size_t)(c0 + r) * 64 + ch);
#pragma unroll
    for (int j = 0; j < 4; j++) {
      float4 f = s4[j];
      tile[r][ch + 4 * j + 0] = (__bf16)f.x;
      tile[r][ch + 4 * j + 1] = (__bf16)f.y;
      tile[r][ch + 4 * j + 2] = (__bf16)f.z;
      tile[r][ch + 4 * j + 3] = (__bf16)f.w;
    }
  }
  __syncthreads();
  const int h = t >> 2;
  const int cc = (t & 3) * 16;
  union { __bf16 o[16]; uint4 u[2]; } pk;
#pragma unroll
  for (int j = 0; j < 16; j++) pk.o[j] = tile[cc + j][h];
  const int n = mat * 64 + h;
  char* base = Wt_s + (size_t)n * 2048 + (c0 >> 6) * 128;
  const int bc = cc * 2;
  *(uint4*)(base + ((bc) ^ ((n & 7) << 4))) = pk.u[0];
  *(uint4*)(base + ((bc + 16) ^ ((n & 7) << 4))) = pk.u[1];
}

// ---------------------------------------------------------------------------
// Kernel 1: FUSED projection + causal attention. One block per batch:
// 128 blocks x 512 threads (8 waves), 112 KB LDS, 1 block/CU.
// Phase 1 (GEMM, R7 pipeline): KQV[256][192] = x[b][256][1024] * W.
//   Wave w owns rows 32w..32w+31, all 192 cols (acc = 6 x f32x16).
//   A: coalesced float4 -> regs (2-deep) -> bf16 -> swizzled LDS dbuf (2x32KB).
//   W: LDS dbuf (2x24KB) via global_load_lds from pre-swizzled Wt_s.
//   Counted-vmcnt barriers: vmcnt(8) keeps the 8 newest A-loads in flight.
// Phase 2: epilogue writes K/V/Q from acc DIRECTLY into LDS (swizzled attn
//   layouts; overlays the GEMM buffers after a barrier). No global KQV.
// Phase 3 (attn, R5 math): wave w = q-rows 32w..32w+31, nf = w+1 frags.
// ---------------------------------------------------------------------------
__launch_bounds__(512, 2)
__global__ void fused_kernel(const float* __restrict__ x, const char* __restrict__ Wt_s,
                             float* __restrict__ out) {
  __shared__ char lds[114688];  // GEMM: A0|A1|W0|W1 = 32|32|24|24 KB
  char* A0 = lds;               // attn overlay: Q | K | Vt = 32|32|32 KB
  char* A1 = lds + 32768;
  char* W0 = lds + 65536;
  char* W1 = lds + 90112;
  char* Qlds = lds;
  char* Klds = lds + 32768;
  char* Vlds = lds + 65536;

  const int tid = threadIdx.x;
  const int lane = tid & 63;
  const int wave = tid >> 6;  // 0..7
  const int b = blockIdx.x;
  const int row0 = b * 256;
  const int hi = lane >> 5;

  // A staging: thread owns row sr (0..255), 32 contiguous floats at col sc*32
  const int sr = tid >> 1;
  const int sc = tid & 1;
  const float4* xp = (const float4*)(x + (size_t)(row0 + sr) * 1024) + sc * 8;

  f32x16 acc[6];
#pragma unroll
  for (int i = 0; i < 6; i++) acc[i] = zero16();

  float4 s0[8], s1[8];  // 2-deep A register ping-pong (32 floats each)

#define SB __builtin_amdgcn_sched_barrier(0)

#define LOADA(rr, T)                                                              \
  {                                                                               \
    _Pragma("unroll") for (int j = 0; j < 8; j++) rr[j] = xp[(T) * 16 + j];       \
  }

  // W tile: 192 rows x 128B = 1536 x 16B chunks; 512 threads x 3 each
#define GW(T, Wbuf)                                                               \
  {                                                                               \
    _Pragma("unroll") for (int j = 0; j < 3; j++) {                               \
      int idx = j * 512 + tid;                                                    \
      GLOAD16(Wt_s + (size_t)(idx >> 3) * 2048 + (T) * 128 + (idx & 7) * 16,      \
              Wbuf + j * 8192 + wave * 1024);                                     \
    }                                                                             \
  }

#define CVTWRITE(rr, Abuf)                                                        \
  {                                                                               \
    union { __bf16 h[32]; uint4 u[4]; } cv;                                       \
    _Pragma("unroll") for (int j = 0; j < 8; j++) {                               \
      cv.h[4 * j + 0] = (__bf16)rr[j].x;                                          \
      cv.h[4 * j + 1] = (__bf16)rr[j].y;                                          \
      cv.h[4 * j + 2] = (__bf16)rr[j].z;                                          \
      cv.h[4 * j + 3] = (__bf16)rr[j].w;                                          \
    }                                                                             \
    _Pragma("unroll") for (int j = 0; j < 4; j++) {                               \
      *(uint4*)(Abuf + sr * 128 + (((sc * 64) + j * 16) ^ ((sr & 7) << 4))) =     \
          cv.u[j];                                                                \
    }                                                                             \
  }

#define MMA(Abuf, Wbuf)                                                           \
  {                                                                               \
    _Pragma("unroll") for (int ks = 0; ks < 4; ks++) {                            \
      int arow = wave * 32 + (lane & 31);                                         \
      int kb = ks * 32 + (hi << 4);                                               \
      v8bf av = *(const v8bf*)(Abuf + arow * 128 + (kb ^ ((arow & 7) << 4)));     \
      _Pragma("unroll") for (int nf = 0; nf < 6; nf++) {                          \
        int brow = nf * 32 + (lane & 31);                                         \
        v8bf bv = *(const v8bf*)(Wbuf + brow * 128 + (kb ^ ((brow & 7) << 4)));   \
        acc[nf] = __builtin_amdgcn_mfma_f32_32x32x16_bf16(av, bv, acc[nf], 0, 0, 0); \
      }                                                                           \
    }                                                                             \
  }

#define BAR8                                                                      \
  do {                                                                            \
    asm volatile("s_waitcnt vmcnt(8) lgkmcnt(0)" ::: "memory");                   \
    __builtin_amdgcn_s_barrier();                                                 \
    SB;                                                                           \
  } while (0)
#define BAR0v                                                                     \
  do {                                                                            \
    asm volatile("s_waitcnt vmcnt(0) lgkmcnt(0)" ::: "memory");                   \
    __builtin_amdgcn_s_barrier();                                                 \
    SB;                                                                           \
  } while (0)

  // STEP T: refill s[T&1] with A(T+2); stage A(T+1) from s[(T+1)&1]; compute T.
#define STEP(T, SCUR, SNXT, ACUR, WCUR, ANXT, WNXT)                               \
  GW(T + 1, WNXT);                                                                \
  SB;                                                                             \
  LOADA(SCUR, (T) + 2);                                                           \
  SB;                                                                             \
  MMA(ACUR, WCUR);                                                                \
  CVTWRITE(SNXT, ANXT);                                                           \
  BAR8;

  // prologue
  GW(0, W0);
  SB;
  LOADA(s0, 0);
  LOADA(s1, 1);
  SB;
  CVTWRITE(s0, A0);
  BAR8;

  STEP(0, s0, s1, A0, W0, A1, W1)
  STEP(1, s1, s0, A1, W1, A0, W0)
  STEP(2, s0, s1, A0, W0, A1, W1)
  STEP(3, s1, s0, A1, W1, A0, W0)
  STEP(4, s0, s1, A0, W0, A1, W1)
  STEP(5, s1, s0, A1, W1, A0, W0)
  STEP(6, s0, s1, A0, W0, A1, W1)
  STEP(7, s1, s0, A1, W1, A0, W0)
  STEP(8, s0, s1, A0, W0, A1, W1)
  STEP(9, s1, s0, A1, W1, A0, W0)
  STEP(10, s0, s1, A0, W0, A1, W1)
  STEP(11, s1, s0, A1, W1, A0, W0)
  STEP(12, s0, s1, A0, W0, A1, W1)
  STEP(13, s1, s0, A1, W1, A0, W0)
  // T=14: no LOADA(16)
  GW(15, W1);
  SB;
  MMA(A0, W0);
  CVTWRITE(s1, A1);
  BAR0v;
  // T=15
  MMA(A1, W1);

  // ---- Phase 2: acc -> LDS (attn layouts). Overlays GEMM buffers. ----
  __syncthreads();  // all MMA ds_reads complete before overwrite
#pragma unroll
  for (int nf = 0; nf < 6; nf++) {
#pragma unroll
    for (int r = 0; r < 16; r++) {
      int g = wave * 32 + (r & 3) + ((r >> 2) << 3) + (hi << 2);
      int col = nf * 32 + (lane & 31);
      __bf16 val = (__bf16)acc[nf][r];
      if (nf < 2) {  // Q: [g][h*2B] swz
        *(__bf16*)(Qlds + g * 128 + ((col * 2) ^ ((g & 7) << 4))) = val;
      } else if (nf < 4) {  // K
        int h = col - 64;
        *(__bf16*)(Klds + g * 128 + ((h * 2) ^ ((g & 7) << 4))) = val;
      } else {  // V transposed: [h][s*2B] swz
        int h = col - 128;
        *(__bf16*)(Vlds + h * 512 + ((g * 2) ^ ((h & 7) << 4))) = val;
      }
    }
  }
  __syncthreads();

  // ---- Phase 3: causal attention (R5 math). Wave w = q-rows 32w..32w+31 ----
  const int t0 = wave * 32;
  const int tg = t0 + (lane & 31);
  const int nfr = wave + 1;

  v8bf bq[4];
  {
    int qrow = wave * 32 + (lane & 31);
#pragma unroll
    for (int ks = 0; ks < 4; ks++) {
      int kbyte = ks * 32 + (hi << 4);
      bq[ks] = *(const v8bf*)(Qlds + qrow * 128 + (kbyte ^ ((qrow & 7) << 4)));
    }
  }

  f32x16 sacc[8];
#pragma unroll
  for (int sf = 0; sf < 8; sf++) {
    f32x16 sv = zero16();
    if (sf < nfr) {
#pragma unroll
      for (int ks = 0; ks < 4; ks++) {
        int kbyte = ks * 32 + (hi << 4);
        int krow = sf * 32 + (lane & 31);
        v8bf a = *(const v8bf*)(Klds + krow * 128 + (kbyte ^ ((krow & 7) << 4)));
        sv = __builtin_amdgcn_mfma_f32_32x32x16_bf16(a, bq[ks], sv, 0, 0, 0);
      }
    }
    sacc[sf] = sv;
  }

  float m = -1e30f;
#pragma unroll
  for (int sf = 0; sf < 8; sf++) {
    if (sf < nfr) {
#pragma unroll
      for (int r = 0; r < 16; r++) {
        int sg = sf * 32 + (r & 3) + ((r >> 2) << 3) + (hi << 2);
        float v = sacc[sf][r] * 0.125f;
        v = (sg > tg) ? -1e30f : v;
        sacc[sf][r] = v;
        m = fmaxf(m, v);
      }
    }
  }
  m = fmaxf(m, __shfl_xor(m, 32, 64));
  float l = 0.f;
#pragma unroll
  for (int sf = 0; sf < 8; sf++) {
    if (sf < nfr) {
#pragma unroll
      for (int r = 0; r < 16; r++) {
        float p = __expf(sacc[sf][r] - m);
        sacc[sf][r] = p;
        l += p;
      }
    }
  }
  l += __shfl_xor(l, 32, 64);
  float inv = 1.0f / l;

  f32x16 oacc[2];
  oacc[0] = zero16();
  oacc[1] = zero16();
  const bool hiLane = (lane >= 32);
#pragma unroll
  for (int sf = 0; sf < 8; sf++) {
    if (sf < nfr) {
      uint w[8], ow[8];
#pragma unroll
      for (int q = 0; q < 4; q++) {
        w[2 * q]     = pack_bf16(sacc[sf][4 * q] * inv,     sacc[sf][4 * q + 1] * inv);
        w[2 * q + 1] = pack_bf16(sacc[sf][4 * q + 2] * inv, sacc[sf][4 * q + 3] * inv);
      }
#pragma unroll
      for (int i = 0; i < 8; i++) ow[i] = (uint)__shfl_xor((int)w[i], 32, 64);
#pragma unroll
      for (int ks = 0; ks < 2; ks++) {
        int bse = 4 * ks;
        union { uint u[4]; v8bf v; } A;
        A.u[0] = hiLane ? ow[bse + 2] : w[bse + 0];
        A.u[1] = hiLane ? ow[bse + 3] : w[bse + 1];
        A.u[2] = hiLane ? w[bse + 2] : ow[bse + 0];
        A.u[3] = hiLane ? w[bse + 3] : ow[bse + 1];
        int sbyte0 = (sf * 32 + ks * 16) * 2 + (hi << 4);
#pragma unroll
        for (int hf = 0; hf < 2; hf++) {
          int vrow = hf * 32 + (lane & 31);
          v8bf bv = *(const v8bf*)(Vlds + vrow * 512 + (sbyte0 ^ ((vrow & 7) << 4)));
          oacc[hf] = __builtin_amdgcn_mfma_f32_32x32x16_bf16(A.v, bv, oacc[hf], 0, 0, 0);
        }
      }
    }
  }

#pragma unroll
  for (int hf = 0; hf < 2; hf++) {
#pragma unroll
    for (int r = 0; r < 16; r++) {
      int t = t0 + (r & 3) + ((r >> 2) << 3) + (hi << 2);
      int h = hf * 32 + (lane & 31);
      out[((size_t)b * 256 + t) * 64 + h] = oacc[hf][r];
    }
  }
#undef STEP
#undef BAR8
#undef BAR0v
#undef LOADA
#undef GW
#undef CVTWRITE
#undef MMA
#undef SB
}

// ---------------------------------------------------------------------------
extern "C" void kernel_launch(void* const* d_in, const int* in_sizes, int n_in,
                              void* d_out, int out_size, void* d_ws, size_t ws_size,
                              hipStream_t stream) {
  const float* x  = (const float*)d_in[0];
  const float* Wk = (const float*)d_in[1];
  const float* Wq = (const float*)d_in[2];
  const float* Wv = (const float*)d_in[3];
  float* out = (float*)d_out;

  char* Wt_s = (char*)d_ws;  // 384 KB

  prep_wt<<<48, 256, 0, stream>>>(Wq, Wk, Wv, Wt_s);
  fused_kernel<<<128, 512, 0, stream>>>(x, Wt_s, out);
}

// Round 15
// 45.700 us; speedup vs baseline: 1.3599x; 1.3599x over previous
//
#include <hip/hip_runtime.h>
#include <hip/hip_bf16.h>

typedef __bf16 v8bf __attribute__((ext_vector_type(8)));
typedef float f32x16 __attribute__((ext_vector_type(16)));
typedef unsigned int uint;
typedef unsigned short ushort;

#define GLOAD16(gsrc, ldst)                                                       \
  __builtin_amdgcn_global_load_lds(                                               \
      (const __attribute__((address_space(1))) unsigned int*)(gsrc),              \
      (__attribute__((address_space(3))) unsigned int*)(ldst), 16, 0, 0)

__device__ inline f32x16 zero16() {
  f32x16 z;
#pragma unroll
  for (int i = 0; i < 16; i++) z[i] = 0.f;
  return z;
}

__device__ inline uint pack_bf16(float a, float b) {
  union { __bf16 h[2]; uint u; } c;
  c.h[0] = (__bf16)a;
  c.h[1] = (__bf16)b;
  return c.u;
}

// ---------------------------------------------------------------------------
// Kernel 0: Wt_s = transpose of [Wq|Wk|Wv] -> bf16, PRE-SWIZZLED:
// element (n,k) at byte n*2048 + (k>>6)*128 + (((k&63)*2) ^ ((n&7)<<4)).
// (R7 — validated, byte-identical)
// ---------------------------------------------------------------------------
__global__ void prep_wt(const float* __restrict__ Wq, const float* __restrict__ Wk,
                        const float* __restrict__ Wv, char* __restrict__ Wt_s) {
  __shared__ __bf16 tile[64][74];
  const int mat = blockIdx.x >> 4;
  const int c0 = (blockIdx.x & 15) * 64;
  const float* src = (mat == 0) ? Wq : (mat == 1) ? Wk : Wv;
  const int t = threadIdx.x;  // 256 threads
  {
    const int r = t >> 2;
    const int ch = (t & 3) * 16;
    const float4* s4 = (const float4*)(src + (size_t)(c0 + r) * 64 + ch);
#pragma unroll
    for (int j = 0; j < 4; j++) {
      float4 f = s4[j];
      tile[r][ch + 4 * j + 0] = (__bf16)f.x;
      tile[r][ch + 4 * j + 1] = (__bf16)f.y;
      tile[r][ch + 4 * j + 2] = (__bf16)f.z;
      tile[r][ch + 4 * j + 3] = (__bf16)f.w;
    }
  }
  __syncthreads();
  const int h = t >> 2;
  const int cc = (t & 3) * 16;
  union { __bf16 o[16]; uint4 u[2]; } pk;
#pragma unroll
  for (int j = 0; j < 16; j++) pk.o[j] = tile[cc + j][h];
  const int n = mat * 64 + h;
  char* base = Wt_s + (size_t)n * 2048 + (c0 >> 6) * 128;
  const int bc = cc * 2;
  *(uint4*)(base + ((bc) ^ ((n & 7) << 4))) = pk.u[0];
  *(uint4*)(base + ((bc + 16) ^ ((n & 7) << 4))) = pk.u[1];
}

// ---------------------------------------------------------------------------
// Kernel 1: KQV[32768][192] = x * W. (R7 — best measured proj, byte-identical)
// 512 blocks x 256 threads, 2 blocks/CU; 4-deep A reg pipe; W dbuf via
// global_load_lds from pre-swizzled Wt_s; counted-vmcnt barriers.
// ---------------------------------------------------------------------------
__launch_bounds__(256, 2)
__global__ void proj_kernel(const float* __restrict__ x, const char* __restrict__ Wt_s,
                            __bf16* __restrict__ KQV) {
  __shared__ char lds[65536];
  char* A0 = lds;            // [64][128B] bf16 swizzled, 8 KB
  char* A1 = lds + 8192;
  char* W0 = lds + 16384;    // [192][128B] bf16 swizzled, 24 KB
  char* W1 = lds + 40960;

  const int tid = threadIdx.x;
  const int lane = tid & 63;
  const int wave = tid >> 6;  // 0..3
  const int wm = wave >> 1;
  const int wn = wave & 1;
  const int row0 = blockIdx.x * 64;

  const int sr = tid >> 2;
  const int sc = tid & 3;
  const float4* xp = (const float4*)(x + (size_t)(row0 + sr) * 1024 + sc * 16);

  f32x16 acc[3];
#pragma unroll
  for (int i = 0; i < 3; i++) acc[i] = zero16();

  float4 s0[4], s1[4], s2[4], s3[4];

#define SB __builtin_amdgcn_sched_barrier(0)

#define LOADA(rr, t)                                                              \
  {                                                                               \
    _Pragma("unroll") for (int j = 0; j < 4; j++) rr[j] = xp[(t) * 16 + j];       \
  }

#define GW(t, Wbuf)                                                               \
  {                                                                               \
    _Pragma("unroll") for (int j = 0; j < 6; j++) {                               \
      int idx = wave * 64 + j * 256 + lane;                                       \
      GLOAD16(Wt_s + (size_t)(idx >> 3) * 2048 + (t) * 128 + (idx & 7) * 16,      \
              Wbuf + wave * 1024 + j * 4096);                                     \
    }                                                                             \
  }

#define CVTWRITE(rr, Abuf)                                                        \
  {                                                                               \
    union { __bf16 h[16]; uint4 u[2]; } cv;                                       \
    _Pragma("unroll") for (int j = 0; j < 4; j++) {                               \
      cv.h[4 * j + 0] = (__bf16)rr[j].x;                                          \
      cv.h[4 * j + 1] = (__bf16)rr[j].y;                                          \
      cv.h[4 * j + 2] = (__bf16)rr[j].z;                                          \
      cv.h[4 * j + 3] = (__bf16)rr[j].w;                                          \
    }                                                                             \
    *(uint4*)(Abuf + sr * 128 + ((sc * 32) ^ ((sr & 7) << 4))) = cv.u[0];         \
    *(uint4*)(Abuf + sr * 128 + ((sc * 32 + 16) ^ ((sr & 7) << 4))) = cv.u[1];    \
  }

#define MMA(Abuf, Wbuf)                                                           \
  {                                                                               \
    _Pragma("unroll") for (int ks = 0; ks < 4; ks++) {                            \
      int arow = wm * 32 + (lane & 31);                                           \
      int kb = ks * 32 + ((lane >> 5) << 4);                                      \
      v8bf av = *(const v8bf*)(Abuf + arow * 128 + (kb ^ ((arow & 7) << 4)));     \
      _Pragma("unroll") for (int nf = 0; nf < 3; nf++) {                          \
        int brow = wn * 96 + nf * 32 + (lane & 31);                               \
        v8bf bv = *(const v8bf*)(Wbuf + brow * 128 + (kb ^ ((brow & 7) << 4)));   \
        acc[nf] = __builtin_amdgcn_mfma_f32_32x32x16_bf16(av, bv, acc[nf], 0, 0, 0); \
      }                                                                           \
    }                                                                             \
  }

#define BAR4                                                                      \
  do {                                                                            \
    asm volatile("s_waitcnt vmcnt(4) lgkmcnt(0)" ::: "memory");                   \
    __builtin_amdgcn_s_barrier();                                                 \
    SB;                                                                           \
  } while (0)
#define BAR0                                                                      \
  do {                                                                            \
    asm volatile("s_waitcnt vmcnt(0) lgkmcnt(0)" ::: "memory");                   \
    __builtin_amdgcn_s_barrier();                                                 \
    SB;                                                                           \
  } while (0)

#define STEP(T, SI, SC_, ACUR, WCUR, ANXT, WNXT)                                  \
  GW(T + 1, WNXT);                                                                \
  SB;                                                                             \
  LOADA(SI, T + 2);                                                               \
  SB;                                                                             \
  MMA(ACUR, WCUR);                                                                \
  CVTWRITE(SC_, ANXT);                                                            \
  BAR4;

  GW(0, W0);
  SB;
  LOADA(s0, 0);
  LOADA(s1, 1);
  SB;
  CVTWRITE(s0, A0);
  BAR4;

  STEP(0, s2, s1, A0, W0, A1, W1)
  STEP(1, s3, s2, A1, W1, A0, W0)
  STEP(2, s0, s3, A0, W0, A1, W1)
  STEP(3, s1, s0, A1, W1, A0, W0)
  STEP(4, s2, s1, A0, W0, A1, W1)
  STEP(5, s3, s2, A1, W1, A0, W0)
  STEP(6, s0, s3, A0, W0, A1, W1)
  STEP(7, s1, s0, A1, W1, A0, W0)
  STEP(8, s2, s1, A0, W0, A1, W1)
  STEP(9, s3, s2, A1, W1, A0, W0)
  STEP(10, s0, s3, A0, W0, A1, W1)
  STEP(11, s1, s0, A1, W1, A0, W0)
  STEP(12, s2, s1, A0, W0, A1, W1)
  STEP(13, s3, s2, A1, W1, A0, W0)
  GW(15, W1);
  SB;
  MMA(A0, W0);
  CVTWRITE(s3, A1);
  BAR0;
  MMA(A1, W1);

  // epilogue: write bf16 KQV
#pragma unroll
  for (int nf = 0; nf < 3; nf++) {
#pragma unroll
    for (int r = 0; r < 16; r++) {
      int row = row0 + wm * 32 + (r & 3) + ((r >> 2) << 3) + ((lane >> 5) << 2);
      int col = wn * 96 + nf * 32 + (lane & 31);
      KQV[(size_t)row * 192 + col] = (__bf16)acc[nf][r];
    }
  }
#undef STEP
#undef BAR4
#undef BAR0
#undef LOADA
#undef GW
#undef CVTWRITE
#undef MMA
#undef SB
}

// ---------------------------------------------------------------------------
// Kernel 2: causal attention. 256 blocks x 256 threads. ONLY change vs R7:
// Q-LDS deleted — Q fragments load direct to registers from KQV (stride 192;
// numerics validated in R13). LDS 80->64 KB => 2 blocks/CU (8 waves/CU),
// giving TLP cover for the staging phase. K/V staging + math unchanged (R5).
// ---------------------------------------------------------------------------
__launch_bounds__(256)
__global__ void attn_kernel(const __bf16* __restrict__ KQV, float* __restrict__ out) {
  __shared__ char lds[65536];  // K:[256][64]swz 32KB | Vt:[64][256]swz 32KB
  char* Klds = lds;
  char* Vlds = lds + 32768;

  const int tid = threadIdx.x;
  const int lane = tid & 63;
  const int wave = tid >> 6;  // 0..3
  const int b = blockIdx.x >> 1;
  const int half = blockIdx.x & 1;
  const int bt0 = half * 128;
  const size_t base = (size_t)b * 256 * 192;
  const int hi = lane >> 5;

  // Q fragments direct to regs (B-operand of swapped QK^T)
  v8bf bq[4];
  {
    const __bf16* qsrc =
        KQV + base + (size_t)(bt0 + wave * 32 + (lane & 31)) * 192 + (hi << 3);
#pragma unroll
    for (int ks = 0; ks < 4; ks++) bq[ks] = *(const v8bf*)(qsrc + ks * 16);
  }

  // K staging: rows (cols 64..127), swizzled row-major [s][h]
  {
    int s = tid;
    const uint4* src = (const uint4*)(KQV + base + (size_t)s * 192 + 64);
#pragma unroll
    for (int i = 0; i < 8; i++) {
      uint4 v = src[i];
      int byte = s * 128 + ((i * 16) ^ ((s & 7) << 4));
      *(uint4*)(Klds + byte) = v;
    }
  }
  // V staging: transpose-scatter Vt[h][s], swizzled
  {
    int s = tid;
    const uint4* src = (const uint4*)(KQV + base + (size_t)s * 192 + 128);
#pragma unroll
    for (int i = 0; i < 8; i++) {
      uint4 v = src[i];
      const ushort* e = (const ushort*)&v;
#pragma unroll
      for (int j = 0; j < 8; j++) {
        int h = i * 8 + j;
        int byte = h * 512 + ((s * 2) ^ ((h & 7) << 4));
        *(ushort*)(Vlds + byte) = e[j];
      }
    }
  }
  __syncthreads();

  const int t0 = bt0 + wave * 32;
  const int tg = t0 + (lane & 31);
  const int nf = (t0 >> 5) + 1;

  f32x16 sacc[8];
#pragma unroll
  for (int sf = 0; sf < 8; sf++) {
    f32x16 sv = zero16();
    if (sf < nf) {
#pragma unroll
      for (int ks = 0; ks < 4; ks++) {
        int kbyte = ks * 32 + (hi << 4);
        int krow = sf * 32 + (lane & 31);
        v8bf a = *(const v8bf*)(Klds + krow * 128 + (kbyte ^ ((krow & 7) << 4)));
        sv = __builtin_amdgcn_mfma_f32_32x32x16_bf16(a, bq[ks], sv, 0, 0, 0);
      }
    }
    sacc[sf] = sv;
  }

  float m = -1e30f;
#pragma unroll
  for (int sf = 0; sf < 8; sf++) {
    if (sf < nf) {
#pragma unroll
      for (int r = 0; r < 16; r++) {
        int sg = sf * 32 + (r & 3) + ((r >> 2) << 3) + (hi << 2);
        float v = sacc[sf][r] * 0.125f;
        v = (sg > tg) ? -1e30f : v;
        sacc[sf][r] = v;
        m = fmaxf(m, v);
      }
    }
  }
  m = fmaxf(m, __shfl_xor(m, 32, 64));
  float l = 0.f;
#pragma unroll
  for (int sf = 0; sf < 8; sf++) {
    if (sf < nf) {
#pragma unroll
      for (int r = 0; r < 16; r++) {
        float p = __expf(sacc[sf][r] - m);
        sacc[sf][r] = p;
        l += p;
      }
    }
  }
  l += __shfl_xor(l, 32, 64);
  float inv = 1.0f / l;

  f32x16 oacc[2];
  oacc[0] = zero16();
  oacc[1] = zero16();
  const bool hiLane = (lane >= 32);
#pragma unroll
  for (int sf = 0; sf < 8; sf++) {
    if (sf < nf) {
      uint w[8], ow[8];
#pragma unroll
      for (int q = 0; q < 4; q++) {
        w[2 * q]     = pack_bf16(sacc[sf][4 * q] * inv,     sacc[sf][4 * q + 1] * inv);
        w[2 * q + 1] = pack_bf16(sacc[sf][4 * q + 2] * inv, sacc[sf][4 * q + 3] * inv);
      }
#pragma unroll
      for (int i = 0; i < 8; i++) ow[i] = (uint)__shfl_xor((int)w[i], 32, 64);
#pragma unroll
      for (int ks = 0; ks < 2; ks++) {
        int bse = 4 * ks;
        union { uint u[4]; v8bf v; } A;
        A.u[0] = hiLane ? ow[bse + 2] : w[bse + 0];
        A.u[1] = hiLane ? ow[bse + 3] : w[bse + 1];
        A.u[2] = hiLane ? w[bse + 2] : ow[bse + 0];
        A.u[3] = hiLane ? w[bse + 3] : ow[bse + 1];
        int sbyte0 = (sf * 32 + ks * 16) * 2 + (hi << 4);
#pragma unroll
        for (int hf = 0; hf < 2; hf++) {
          int vrow = hf * 32 + (lane & 31);
          v8bf bv = *(const v8bf*)(Vlds + vrow * 512 + (sbyte0 ^ ((vrow & 7) << 4)));
          oacc[hf] = __builtin_amdgcn_mfma_f32_32x32x16_bf16(A.v, bv, oacc[hf], 0, 0, 0);
        }
      }
    }
  }

#pragma unroll
  for (int hf = 0; hf < 2; hf++) {
#pragma unroll
    for (int r = 0; r < 16; r++) {
      int t = t0 + (r & 3) + ((r >> 2) << 3) + (hi << 2);
      int h = hf * 32 + (lane & 31);
      out[((size_t)b * 256 + t) * 64 + h] = oacc[hf][r];
    }
  }
}

// ---------------------------------------------------------------------------
extern "C" void kernel_launch(void* const* d_in, const int* in_sizes, int n_in,
                              void* d_out, int out_size, void* d_ws, size_t ws_size,
                              hipStream_t stream) {
  const float* x  = (const float*)d_in[0];
  const float* Wk = (const float*)d_in[1];
  const float* Wq = (const float*)d_in[2];
  const float* Wv = (const float*)d_in[3];
  float* out = (float*)d_out;

  // workspace: KQV bf16 [32768][192] (12.58 MB), then pre-swizzled Wt (384 KB)
  __bf16* KQV = (__bf16*)d_ws;
  char* Wt_s  = (char*)d_ws + (size_t)32768 * 192 * 2;

  prep_wt<<<48, 256, 0, stream>>>(Wq, Wk, Wv, Wt_s);
  proj_kernel<<<512, 256, 0, stream>>>(x, Wt_s, KQV);
  attn_kernel<<<256, 256, 0, stream>>>(KQV, out);
}